// Round 9
// baseline (221.431 us; speedup 1.0000x reference)
//
#include <hip/hip_runtime.h>
#include <hip/hip_fp16.h>

// ModulatedDeformConv (DCNv2) — f16 MFMA, M=128 row-tile, 4m x 2n waves,
// coalesced+prefetched B fragments. 2 dispatches.
// B=4, C=128, H=W=128, Cout=128, DG=8 (Cg=16), 3x3, stride=1, pad=1, dil=1.
//
// prep: blocks 0-127: weight fp32 [o][c*9+k] -> f16 wf[g][ks][kq][cout][8]
//   (B-fragment-ordered, K-pad zeroed: one wave B-load = 2x256B segments);
//   blocks 128-639: x fp32 (B,C,H,W) -> f16 x_t (B,DG,H,W,Cg).
// dcn_main: 512 blocks x 512 thr (8 waves); block = one output row (b,ho):
//   M=128 x N=128, 8 chunks (1 group, K=160 padded). Per chunk: prefetch 10
//   B-frags to regs (latency hidden under sampling), sample S[128][168] f16,
//   prefetch next chunk's offsets, barrier, 5 ksteps mfma_f32_16x16x32_f16.
//   Wave wv: m-subtiles [(wv&1)*4, +4), couts [(wv>>1)*32, +32)
//   -> A ds_reads halved vs R6 (shared across 2 n-subtiles).

#define NB    4
#define NC    128
#define NH    128
#define NW    128
#define NCOUT 128
#define NDG   8
#define NCG   16
#define NK    9
#define NCK   1152
#define NHW   16384
#define GK    160            // padded K per group
#define ROWP  168            // S row stride in f16 (336 B, 16B-aligned)

typedef __attribute__((ext_vector_type(4))) float f32x4;
typedef _Float16 half8 __attribute__((ext_vector_type(8)));

union C16 { uint4 u[2]; __half2 h[8]; };

__device__ __forceinline__ unsigned pk2h(float a, float b) {
  return (unsigned)__half_as_ushort(__float2half_rn(a)) |
         ((unsigned)__half_as_ushort(__float2half_rn(b)) << 16);
}

// ---------------- fused prep ----------------
__global__ __launch_bounds__(256)
void prep(const float* __restrict__ x, const float* __restrict__ w,
          ushort* __restrict__ xt, ushort* __restrict__ wf) {
  __shared__ __align__(16) unsigned LDSU[1024 * 9];   // 36,864 B
  const int tid = threadIdx.x;

  if (blockIdx.x < 128) {
    // weight: [o][c*9+k] -> wf[((g*5+ks)*4+kq)*128 + o][8 f16], pad = 0
    const int o = blockIdx.x;
    float* WL = (float*)LDSU;
    const float4* src = (const float4*)(w + o * NCK);
    for (int i = tid; i < NCK / 4; i += 256) ((float4*)WL)[i] = src[i];
    __syncthreads();
    unsigned* dstw = (unsigned*)wf;
    for (int t = tid; t < 640; t += 256) {     // t = g*80 + r, r = kcol/2
      const int g = t / 80, r = t - g * 80;
      unsigned v = 0;
      if (r < 72) {
        const int k = r >> 3;
        const int c = g * NCG + (r & 7) * 2;
        v = pk2h(WL[c * NK + k], WL[(c + 1) * NK + k]);
      }
      const int ks = r >> 4;
      const int kq = (r >> 2) & 3;
      const int ep = r & 3;
      dstw[((((g * 5 + ks) * 4 + kq) * 128) + o) * 4 + ep] = v;
    }
  } else {
    // x transpose: (B,C,H,W) fp32 -> (B,DG,H,W,Cg) f16
    const int blk  = blockIdx.x - 128;                 // 0..511
    const int slab = blk >> 4;                         // b*8+g
    const int hw0  = (blk & 15) * 1024;
    const float* xb = x + (size_t)slab * NCG * NHW + hw0;
#pragma unroll
    for (int cp = 0; cp < 8; ++cp) {
#pragma unroll
      for (int i = 0; i < 4; ++i) {
        const int hw = tid + 256 * i;
        LDSU[hw * 9 + cp] =
            pk2h(xb[(2 * cp) * NHW + hw], xb[(2 * cp + 1) * NHW + hw]);
      }
    }
    __syncthreads();
    uint4* dst = (uint4*)(xt + ((size_t)slab * NHW + hw0) * NCG);
#pragma unroll
    for (int j = 0; j < 8; ++j) {
      const int lin = tid + 256 * j;
      const int hw = lin >> 1, q = lin & 1;
      uint4 v;
      v.x = LDSU[hw * 9 + q * 4 + 0];
      v.y = LDSU[hw * 9 + q * 4 + 1];
      v.z = LDSU[hw * 9 + q * 4 + 2];
      v.w = LDSU[hw * 9 + q * 4 + 3];
      dst[lin] = v;
    }
  }
}

// ---------------- main ----------------
__device__ __forceinline__ void sample_one(
    int p, int k, int g, int b, int ho, float dy, float dx, float mm,
    const ushort* __restrict__ xt, ushort* __restrict__ S) {
  const int ky = k / 3, kx = k - ky * 3;

  const float sy = dy + (float)(ho - 1 + ky);
  const float sx = dx + (float)(p - 1 + kx);
  const float y0f = floorf(sy), x0f = floorf(sx);
  const float ly = sy - y0f, lx = sx - x0f;
  const int y0 = (int)y0f, x0 = (int)x0f;
  const int y1 = y0 + 1,  x1 = x0 + 1;
  const float hy = 1.f - ly, hx = 1.f - lx;

  float w00 = hy * hx * mm, w01 = hy * lx * mm;
  float w10 = ly * hx * mm, w11 = ly * lx * mm;
  if (y0 < 0 || y0 >= NH) { w00 = 0.f; w01 = 0.f; }
  if (y1 < 0 || y1 >= NH) { w10 = 0.f; w11 = 0.f; }
  if (x0 < 0 || x0 >= NW) { w00 = 0.f; w10 = 0.f; }
  if (x1 < 0 || x1 >= NW) { w01 = 0.f; w11 = 0.f; }

  const int yc0 = min(max(y0, 0), NH - 1);
  const int yc1 = min(max(y1, 0), NH - 1);
  const int xc0 = min(max(x0, 0), NW - 1);
  const int xc1 = min(max(x1, 0), NW - 1);

  const ushort* xg = xt + (size_t)(b * NDG + g) * NHW * NCG;
  const uint4* q00 = (const uint4*)(xg + (yc0 * NW + xc0) * NCG);
  const uint4* q01 = (const uint4*)(xg + (yc0 * NW + xc1) * NCG);
  const uint4* q10 = (const uint4*)(xg + (yc1 * NW + xc0) * NCG);
  const uint4* q11 = (const uint4*)(xg + (yc1 * NW + xc1) * NCG);

  C16 v00, v01, v10, v11, r;
  v00.u[0] = q00[0]; v00.u[1] = q00[1];
  v01.u[0] = q01[0]; v01.u[1] = q01[1];
  v10.u[0] = q10[0]; v10.u[1] = q10[1];
  v11.u[0] = q11[0]; v11.u[1] = q11[1];

  const __half2 W00 = __float2half2_rn(w00);
  const __half2 W01 = __float2half2_rn(w01);
  const __half2 W10 = __float2half2_rn(w10);
  const __half2 W11 = __float2half2_rn(w11);
#pragma unroll
  for (int i = 0; i < 8; ++i) {
    __half2 a = __hmul2(v00.h[i], W00);
    a = __hfma2(v01.h[i], W01, a);
    a = __hfma2(v10.h[i], W10, a);
    a = __hfma2(v11.h[i], W11, a);
    r.h[i] = a;
  }
  ushort* dp = &S[p * ROWP + k * 16];
  *(uint4*)dp = r.u[0];
  *((uint4*)dp + 1) = r.u[1];
}

__global__ __launch_bounds__(512, 4)
void dcn_main(const float* __restrict__ off,
              const float* __restrict__ msk,
              const ushort* __restrict__ xt,   // f16 (B,DG,H,W,Cg)
              const ushort* __restrict__ wf,   // f16 B-frag layout
              const float* __restrict__ bias,
              float* __restrict__ out) {
  __shared__ __align__(16) ushort S[128 * ROWP];   // 43,008 B

  const int tid  = threadIdx.x;
  // XCD-aware swizzle (bijective: 512 = 8 * 64)
  const int blk0 = blockIdx.x;
  const int blk  = (blk0 & 7) * 64 + (blk0 >> 3);
  const int b    = blk >> 7;                       // 0..3
  const int ho   = blk & 127;

  const int lane = tid & 63;
  const int wv   = tid >> 6;                       // 0..7
  const int l15  = lane & 15;
  const int kq   = lane >> 4;
  const int mh   = (wv & 1) * 4;                   // m-subtile offset (0 / 4)
  const int nb   = wv >> 1;                        // cout quad (0..3)
  const int cbase = nb * 32 + l15;

  const float* offB = off + (size_t)b * 144 * NHW + ho * NW;
  const float* mskB = msk + (size_t)b * 72  * NHW + ho * NW;

  // zero K-pad cols [144,160) of each of 128 rows (wf pad is also 0)
  for (int i = tid; i < 128 * 8; i += 512) {
    ((unsigned*)S)[(i >> 3) * (ROWP / 2) + 72 + (i & 7)] = 0;
  }

  f32x4 acc[4][2];
#pragma unroll
  for (int m = 0; m < 4; ++m) {
    acc[m][0] = {0.f, 0.f, 0.f, 0.f};
    acc[m][1] = {0.f, 0.f, 0.f, 0.f};
  }

  // sampling task map: t in {tid, tid+512, tid+1024(tid<128)}; p=t&127,k=t>>7
  const int p0 = tid & 127;
  const int k0 = tid >> 7;                         // 0..3
  const int k1 = k0 + 4;                           // 4..7

  float dy0, dx0, mm0, dy1, dx1, mm1, dy2 = 0.f, dx2 = 0.f, mm2 = 0.f;
  {
    dy0 = offB[(k0 * 2) * NHW + p0];
    dx0 = offB[(k0 * 2 + 1) * NHW + p0];
    mm0 = mskB[k0 * NHW + p0];
    dy1 = offB[(k1 * 2) * NHW + p0];
    dx1 = offB[(k1 * 2 + 1) * NHW + p0];
    mm1 = mskB[k1 * NHW + p0];
    if (tid < 128) {
      dy2 = offB[16 * NHW + p0];
      dx2 = offB[17 * NHW + p0];
      mm2 = mskB[8 * NHW + p0];
    }
  }

  for (int g = 0; g < 8; ++g) {
    if (g) __syncthreads();                        // MFMA(g-1) done with S

    // ---- prefetch this chunk's 10 B-fragments (drain during sampling) ----
    half8 bf0[5], bf1[5];
    {
      const ushort* wb = wf + ((size_t)(g * 20 + kq) * 128 + cbase) * 8;
#pragma unroll
      for (int ks = 0; ks < 5; ++ks) {
        bf0[ks] = *(const half8*)(wb + ks * 4096);
        bf1[ks] = *(const half8*)(wb + ks * 4096 + 128);   // +16 couts
      }
    }

    // ---- Phase A: sample chunk g with prefetched offsets ----
    sample_one(p0, k0, g, b, ho, dy0, dx0, mm0, xt, S);
    sample_one(p0, k1, g, b, ho, dy1, dx1, mm1, xt, S);
    if (tid < 128) sample_one(p0, 8, g, b, ho, dy2, dx2, mm2, xt, S);

    // ---- prefetch offsets for chunk g+1 ----
    if (g < 7) {
      const int gka = (g + 1) * 9 + k0, gkb = (g + 1) * 9 + k1;
      dy0 = offB[(gka * 2) * NHW + p0];
      dx0 = offB[(gka * 2 + 1) * NHW + p0];
      mm0 = mskB[gka * NHW + p0];
      dy1 = offB[(gkb * 2) * NHW + p0];
      dx1 = offB[(gkb * 2 + 1) * NHW + p0];
      mm1 = mskB[gkb * NHW + p0];
      if (tid < 128) {
        const int gkc = (g + 1) * 9 + 8;
        dy2 = offB[(gkc * 2) * NHW + p0];
        dx2 = offB[(gkc * 2 + 1) * NHW + p0];
        mm2 = mskB[gkc * NHW + p0];
      }
    }
    __syncthreads();

    // ---- Phase B: 5 ksteps; wave: m-subtiles mh..mh+3, couts cbase(+16) ----
    const ushort* sa = &S[l15 * ROWP + kq * 8];
#pragma unroll
    for (int ks = 0; ks < 5; ++ks) {
#pragma unroll
      for (int m = 0; m < 4; ++m) {
        const half8 a = *(const half8*)(sa + (mh + m) * 16 * ROWP + ks * 32);
        acc[m][0] = __builtin_amdgcn_mfma_f32_16x16x32_f16(a, bf0[ks], acc[m][0], 0, 0, 0);
        acc[m][1] = __builtin_amdgcn_mfma_f32_16x16x32_f16(a, bf1[ks], acc[m][1], 0, 0, 0);
      }
    }
  }

  // ---- epilogue: D col = l15 (cout_local), row = kq*4+reg = wo in subtile ----
#pragma unroll
  for (int j = 0; j < 2; ++j) {
    const int c0 = nb * 32 + j * 16 + l15;
    const float bs = bias[c0];
    float* op = out + (size_t)(b * NCOUT + c0) * NHW + ho * NW + kq * 4;
#pragma unroll
    for (int m = 0; m < 4; ++m) {
      float4 r = {acc[m][j][0] + bs, acc[m][j][1] + bs,
                  acc[m][j][2] + bs, acc[m][j][3] + bs};
      *(float4*)(op + (mh + m) * 16) = r;
    }
  }
}

extern "C" void kernel_launch(void* const* d_in, const int* in_sizes, int n_in,
                              void* d_out, int out_size, void* d_ws, size_t ws_size,
                              hipStream_t stream) {
  const float* x    = (const float*)d_in[0];
  const float* off  = (const float*)d_in[1];
  const float* msk  = (const float*)d_in[2];
  const float* wgt  = (const float*)d_in[3];
  const float* bias = (const float*)d_in[4];
  float* out = (float*)d_out;

  ushort* xt = (ushort*)d_ws;                          // 16,777,216 B
  ushort* wf = xt + (size_t)NB * NDG * NHW * NCG;      // +327,680 B

  hipLaunchKernelGGL(prep, dim3(640), dim3(256), 0, stream, x, wgt, xt, wf);
  hipLaunchKernelGGL(dcn_main, dim3(512), dim3(512), 0, stream,
                     off, msk, xt, wf, bias, out);
}

// Round 10
// 186.513 us; speedup vs baseline: 1.1872x; 1.1872x over previous
//
#include <hip/hip_runtime.h>
#include <hip/hip_fp16.h>

// ModulatedDeformConv (DCNv2) — 32x32x16 f16 MFMA, M=128 row-tile.
// B=4, C=128, H=W=128, Cout=128, DG=8 (Cg=16), 3x3, stride=1, pad=1, dil=1.
//
// prep: blocks 0-127: weight fp32 [o][c*9+k] -> f16 fragment-ordered
//   wf[(g*10+ks)*2+khalf][cout][8]  (ks=9 pad frag zeroed; one wave B-load =
//   two contiguous 512B segments); blocks 128-639: x fp32 (B,C,H,W) ->
//   f16 x_t (B,DG,H,W,Cg).
// dcn_main: 512 blocks x 512 thr (8 waves); block = one output row (b,ho):
//   M=128 x N=128, 8 chunks (1 group, K=160 padded = 10 ksteps of 16).
//   Per chunk: sample S[128][168] f16, prefetch next chunk's offsets,
//   barrier, 10 ksteps of mfma_f32_32x32x16_f16. Wave wv: n-subtile
//   (wv&3)*32 couts x m-subtiles {2*(wv>>2), +1}; B-frag loaded inline
//   (no reg-array prefetch — R9 spilled) and shared across the 2 MFMAs.
//   32x32 tile halves A-ds_read bytes per MAC vs 16x16 (R6 bottleneck).

#define NB    4
#define NC    128
#define NH    128
#define NW    128
#define NCOUT 128
#define NDG   8
#define NCG   16
#define NK    9
#define NCK   1152
#define NHW   16384
#define GK    160            // padded K per group (10 ksteps x 16)
#define ROWP  168            // S row stride in f16 (336 B, 16B-aligned)

typedef __attribute__((ext_vector_type(16))) float f32x16;
typedef _Float16 half8 __attribute__((ext_vector_type(8)));

union C16 { uint4 u[2]; __half2 h[8]; };

__device__ __forceinline__ unsigned pk2h(float a, float b) {
  return (unsigned)__half_as_ushort(__float2half_rn(a)) |
         ((unsigned)__half_as_ushort(__float2half_rn(b)) << 16);
}

// ---------------- fused prep ----------------
__global__ __launch_bounds__(256)
void prep(const float* __restrict__ x, const float* __restrict__ w,
          ushort* __restrict__ xt, ushort* __restrict__ wf) {
  __shared__ __align__(16) unsigned LDSU[1024 * 9];   // 36,864 B
  const int tid = threadIdx.x;

  if (blockIdx.x < 128) {
    // weight -> wf[frag][cout][8], frag = (g*10+ks)*2+khalf, ks==9 -> 0
    const int o = blockIdx.x;
    float* WL = (float*)LDSU;
    const float4* src = (const float4*)(w + o * NCK);
    for (int i = tid; i < NCK / 4; i += 256) ((float4*)WL)[i] = src[i];
    __syncthreads();
    unsigned* dstw = (unsigned*)wf;
    for (int t = tid; t < 640; t += 256) {     // frag(160) x pair(4)
      const int frag  = t >> 2;
      const int pairI = t & 3;
      const int khalf = frag & 1;
      const int fk    = frag >> 1;
      const int g     = fk / 10;
      const int ks    = fk - g * 10;
      unsigned v = 0;
      if (ks < 9) {
        const int c = g * NCG + khalf * 8 + pairI * 2;
        v = pk2h(WL[c * NK + ks], WL[(c + 1) * NK + ks]);
      }
      dstw[frag * 512 + o * 4 + pairI] = v;
    }
  } else {
    // x transpose: (B,C,H,W) fp32 -> (B,DG,H,W,Cg) f16
    const int blk  = blockIdx.x - 128;                 // 0..511
    const int slab = blk >> 4;                         // b*8+g
    const int hw0  = (blk & 15) * 1024;
    const float* xb = x + (size_t)slab * NCG * NHW + hw0;
#pragma unroll
    for (int cp = 0; cp < 8; ++cp) {
#pragma unroll
      for (int i = 0; i < 4; ++i) {
        const int hw = tid + 256 * i;
        LDSU[hw * 9 + cp] =
            pk2h(xb[(2 * cp) * NHW + hw], xb[(2 * cp + 1) * NHW + hw]);
      }
    }
    __syncthreads();
    uint4* dst = (uint4*)(xt + ((size_t)slab * NHW + hw0) * NCG);
#pragma unroll
    for (int j = 0; j < 8; ++j) {
      const int lin = tid + 256 * j;
      const int hw = lin >> 1, q = lin & 1;
      uint4 v;
      v.x = LDSU[hw * 9 + q * 4 + 0];
      v.y = LDSU[hw * 9 + q * 4 + 1];
      v.z = LDSU[hw * 9 + q * 4 + 2];
      v.w = LDSU[hw * 9 + q * 4 + 3];
      dst[lin] = v;
    }
  }
}

// ---------------- main ----------------
__device__ __forceinline__ void sample_one(
    int p, int k, int g, int b, int ho, float dy, float dx, float mm,
    const ushort* __restrict__ xt, ushort* __restrict__ S) {
  const int ky = k / 3, kx = k - ky * 3;

  const float sy = dy + (float)(ho - 1 + ky);
  const float sx = dx + (float)(p - 1 + kx);
  const float y0f = floorf(sy), x0f = floorf(sx);
  const float ly = sy - y0f, lx = sx - x0f;
  const int y0 = (int)y0f, x0 = (int)x0f;
  const int y1 = y0 + 1,  x1 = x0 + 1;
  const float hy = 1.f - ly, hx = 1.f - lx;

  float w00 = hy * hx * mm, w01 = hy * lx * mm;
  float w10 = ly * hx * mm, w11 = ly * lx * mm;
  if (y0 < 0 || y0 >= NH) { w00 = 0.f; w01 = 0.f; }
  if (y1 < 0 || y1 >= NH) { w10 = 0.f; w11 = 0.f; }
  if (x0 < 0 || x0 >= NW) { w00 = 0.f; w10 = 0.f; }
  if (x1 < 0 || x1 >= NW) { w01 = 0.f; w11 = 0.f; }

  const int yc0 = min(max(y0, 0), NH - 1);
  const int yc1 = min(max(y1, 0), NH - 1);
  const int xc0 = min(max(x0, 0), NW - 1);
  const int xc1 = min(max(x1, 0), NW - 1);

  const ushort* xg = xt + (size_t)(b * NDG + g) * NHW * NCG;
  const uint4* q00 = (const uint4*)(xg + (yc0 * NW + xc0) * NCG);
  const uint4* q01 = (const uint4*)(xg + (yc0 * NW + xc1) * NCG);
  const uint4* q10 = (const uint4*)(xg + (yc1 * NW + xc0) * NCG);
  const uint4* q11 = (const uint4*)(xg + (yc1 * NW + xc1) * NCG);

  C16 v00, v01, v10, v11, r;
  v00.u[0] = q00[0]; v00.u[1] = q00[1];
  v01.u[0] = q01[0]; v01.u[1] = q01[1];
  v10.u[0] = q10[0]; v10.u[1] = q10[1];
  v11.u[0] = q11[0]; v11.u[1] = q11[1];

  const __half2 W00 = __float2half2_rn(w00);
  const __half2 W01 = __float2half2_rn(w01);
  const __half2 W10 = __float2half2_rn(w10);
  const __half2 W11 = __float2half2_rn(w11);
#pragma unroll
  for (int i = 0; i < 8; ++i) {
    __half2 a = __hmul2(v00.h[i], W00);
    a = __hfma2(v01.h[i], W01, a);
    a = __hfma2(v10.h[i], W10, a);
    a = __hfma2(v11.h[i], W11, a);
    r.h[i] = a;
  }
  ushort* dp = &S[p * ROWP + k * 16];
  *(uint4*)dp = r.u[0];
  *((uint4*)dp + 1) = r.u[1];
}

__global__ __launch_bounds__(512, 4)
void dcn_main(const float* __restrict__ off,
              const float* __restrict__ msk,
              const ushort* __restrict__ xt,   // f16 (B,DG,H,W,Cg)
              const ushort* __restrict__ wf,   // f16 fragment-ordered
              const float* __restrict__ bias,
              float* __restrict__ out) {
  __shared__ __align__(16) ushort S[128 * ROWP];   // 43,008 B

  const int tid  = threadIdx.x;
  // XCD-aware swizzle (bijective: 512 = 8 * 64)
  const int blk0 = blockIdx.x;
  const int blk  = (blk0 & 7) * 64 + (blk0 >> 3);
  const int b    = blk >> 7;                       // 0..3
  const int ho   = blk & 127;

  const int lane  = tid & 63;
  const int wv    = tid >> 6;                      // 0..7
  const int l31   = lane & 31;
  const int hi    = lane >> 5;                     // K-half
  const int nbase = (wv & 3) * 32;                 // n-subtile (32 couts)
  const int mpair = wv >> 2;                       // m-subtiles {2*mpair,+1}

  const float* offB = off + (size_t)b * 144 * NHW + ho * NW;
  const float* mskB = msk + (size_t)b * 72  * NHW + ho * NW;

  // zero K-pad cols [144,160) of each of 128 rows (wf ks=9 frag is also 0)
  for (int i = tid; i < 1024; i += 512) {
    ((unsigned*)S)[(i >> 3) * (ROWP / 2) + 72 + (i & 7)] = 0;
  }

  f32x16 acc0, acc1;
#pragma unroll
  for (int i = 0; i < 16; ++i) { acc0[i] = 0.f; acc1[i] = 0.f; }

  // sampling task map: t in {tid, tid+512, tid+1024(tid<128)}; p=t&127,k=t>>7
  const int p0 = tid & 127;
  const int k0 = tid >> 7;                         // 0..3
  const int k1 = k0 + 4;                           // 4..7

  float dy0, dx0, mm0, dy1, dx1, mm1, dy2 = 0.f, dx2 = 0.f, mm2 = 0.f;
  {
    dy0 = offB[(k0 * 2) * NHW + p0];
    dx0 = offB[(k0 * 2 + 1) * NHW + p0];
    mm0 = mskB[k0 * NHW + p0];
    dy1 = offB[(k1 * 2) * NHW + p0];
    dx1 = offB[(k1 * 2 + 1) * NHW + p0];
    mm1 = mskB[k1 * NHW + p0];
    if (tid < 128) {
      dy2 = offB[16 * NHW + p0];
      dx2 = offB[17 * NHW + p0];
      mm2 = mskB[8 * NHW + p0];
    }
  }

  for (int g = 0; g < 8; ++g) {
    if (g) __syncthreads();                        // MFMA(g-1) done with S

    // ---- Phase A: sample chunk g with prefetched offsets ----
    sample_one(p0, k0, g, b, ho, dy0, dx0, mm0, xt, S);
    sample_one(p0, k1, g, b, ho, dy1, dx1, mm1, xt, S);
    if (tid < 128) sample_one(p0, 8, g, b, ho, dy2, dx2, mm2, xt, S);

    // ---- prefetch offsets for chunk g+1 ----
    if (g < 7) {
      const int gka = (g + 1) * 9 + k0, gkb = (g + 1) * 9 + k1;
      dy0 = offB[(gka * 2) * NHW + p0];
      dx0 = offB[(gka * 2 + 1) * NHW + p0];
      mm0 = mskB[gka * NHW + p0];
      dy1 = offB[(gkb * 2) * NHW + p0];
      dx1 = offB[(gkb * 2 + 1) * NHW + p0];
      mm1 = mskB[gkb * NHW + p0];
      if (tid < 128) {
        const int gkc = (g + 1) * 9 + 8;
        dy2 = offB[(gkc * 2) * NHW + p0];
        dx2 = offB[(gkc * 2 + 1) * NHW + p0];
        mm2 = mskB[gkc * NHW + p0];
      }
    }
    __syncthreads();

    // ---- Phase B: 10 ksteps of mfma_f32_32x32x16_f16 ----
    // B-frag: frag = (g*10+ks)*2 + hi, lane reads cout nbase+l31 (512B seg)
    const ushort* wb  = wf + ((size_t)(g * 10) * 2 + hi) * 1024
                           + (nbase + l31) * 8;
    // A-frag: row = m*32 + l31, k = ks*16 + hi*8
    const ushort* sa0 = &S[(mpair * 64 + l31) * ROWP + hi * 8];
    const ushort* sa1 = sa0 + 32 * ROWP;
#pragma unroll
    for (int ks = 0; ks < 10; ++ks) {
      const half8 bfrag = *(const half8*)(wb + ks * 2048);
      const half8 a0 = *(const half8*)(sa0 + ks * 16);
      const half8 a1 = *(const half8*)(sa1 + ks * 16);
      acc0 = __builtin_amdgcn_mfma_f32_32x32x16_f16(a0, bfrag, acc0, 0, 0, 0);
      acc1 = __builtin_amdgcn_mfma_f32_32x32x16_f16(a1, bfrag, acc1, 0, 0, 0);
    }
  }

  // ---- epilogue: D col = l31 (cout_local), row = (reg&3)+8*(reg>>2)+4*hi ----
  const int cout = nbase + l31;
  const float bs = bias[cout];
  float* opb = out + (size_t)(b * NCOUT + cout) * NHW + ho * NW;
#pragma unroll
  for (int j = 0; j < 2; ++j) {
    const f32x16 a = j ? acc1 : acc0;
    float* op = opb + (mpair * 2 + j) * 32 + hi * 4;
#pragma unroll
    for (int r4 = 0; r4 < 4; ++r4) {
      float4 r = {a[r4 * 4 + 0] + bs, a[r4 * 4 + 1] + bs,
                  a[r4 * 4 + 2] + bs, a[r4 * 4 + 3] + bs};
      *(float4*)(op + r4 * 8) = r;
    }
  }
}

extern "C" void kernel_launch(void* const* d_in, const int* in_sizes, int n_in,
                              void* d_out, int out_size, void* d_ws, size_t ws_size,
                              hipStream_t stream) {
  const float* x    = (const float*)d_in[0];
  const float* off  = (const float*)d_in[1];
  const float* msk  = (const float*)d_in[2];
  const float* wgt  = (const float*)d_in[3];
  const float* bias = (const float*)d_in[4];
  float* out = (float*)d_out;

  ushort* xt = (ushort*)d_ws;                          // 16,777,216 B
  ushort* wf = xt + (size_t)NB * NDG * NHW * NCG;      // +327,680 B

  hipLaunchKernelGGL(prep, dim3(640), dim3(256), 0, stream, x, wgt, xt, wf);
  hipLaunchKernelGGL(dcn_main, dim3(512), dim3(512), 0, stream,
                     off, msk, xt, wf, bias, out);
}